// Round 1
// baseline (1151.242 us; speedup 1.0000x reference)
//
#include <hip/hip_runtime.h>
#include <hip/hip_bf16.h>
#include <math.h>

// MoE top-2 SwiGLU, sparse (grouped-by-expert) execution.
// T=2048 tokens, H=1024, I=2048, E=16 experts, K=2.
//
// Pipeline:
//   1) router_kernel:  logits = x @ w_router, top-2, renorm weights
//                      (renorm == softmax over the top-2 logits; global
//                      softmax denominator cancels)
//   2) scatter_kernel: bucket (token,k) assignments by expert -> contiguous
//                      row lists per expert
//   3) gateup_kernel:  h1[row] = silu(x@wg_e) * (x@wu_e) * combine_w  (fp32)
//   4) down_kernel:    y[token] += h1[row] @ wd_e   (atomicAdd scatter)
//
// Round 0: fp32 vector compute baseline (correctness anchor). bf16 MFMA later.

#define T_TOK 2048
#define H_DIM 1024
#define I_DIM 2048
#define E_NUM 16
#define K_TOP 2
#define N_ASSIGN (T_TOK * K_TOP)

// ---------------- workspace layout (bytes) ----------------
// [0,64)            counts      int[16]
// [64,256)          offsets     int[17]
// [256,16640)       topk_idx    int[4096]
// [16640,33024)     topk_w      float[4096]
// [33024,49408)     row_token   int[4096]
// [49408,65792)     row_w       float[4096]
// [65792, +32MiB)   h1          float[4096*2048]
#define WS_OFF_COUNTS   0
#define WS_OFF_OFFSETS  64
#define WS_OFF_TOPKIDX  256
#define WS_OFF_TOPKW    16640
#define WS_OFF_ROWTOK   33024
#define WS_OFF_ROWW     49408
#define WS_OFF_H1       65792

// ---------------------------------------------------------------------------
// Kernel 1: router. One wave (64 threads) per token.
// ---------------------------------------------------------------------------
__global__ __launch_bounds__(64)
void router_kernel(const float* __restrict__ x,
                   const float* __restrict__ wr,
                   int* __restrict__ counts,
                   int* __restrict__ topk_idx,
                   float* __restrict__ topk_w) {
    const int t = blockIdx.x;
    const int lane = threadIdx.x;  // 0..63
    const float* xt = x + (size_t)t * H_DIM;

    float acc[E_NUM];
#pragma unroll
    for (int e = 0; e < E_NUM; e++) acc[e] = 0.f;

    for (int h = lane; h < H_DIM; h += 64) {
        const float xv = xt[h];
        const float* wrow = wr + h * E_NUM;
#pragma unroll
        for (int e = 0; e < E_NUM; e++) acc[e] += xv * wrow[e];
    }

    // wave64 butterfly reduce each of the 16 logits
#pragma unroll
    for (int off = 32; off > 0; off >>= 1) {
#pragma unroll
        for (int e = 0; e < E_NUM; e++)
            acc[e] += __shfl_down(acc[e], off);
    }

    if (lane == 0) {
        // top-2 of logits (probs monotone in logits); ties -> lowest index,
        // matching jax.lax.top_k
        int e0 = 0; float l0 = acc[0];
        for (int e = 1; e < E_NUM; e++)
            if (acc[e] > l0) { l0 = acc[e]; e0 = e; }
        int e1 = (e0 == 0) ? 1 : 0;
        float l1 = acc[e1];
        for (int e = 0; e < E_NUM; e++)
            if (e != e0 && acc[e] > l1) { l1 = acc[e]; e1 = e; }
        // renormalized top-2 weights = softmax over {l0,l1}; l1-l0 <= 0
        const float w0 = 1.f / (1.f + __expf(l1 - l0));
        const float w1 = 1.f - w0;
        topk_idx[t * 2 + 0] = e0;
        topk_idx[t * 2 + 1] = e1;
        topk_w[t * 2 + 0] = w0;
        topk_w[t * 2 + 1] = w1;
        atomicAdd(&counts[e0], 1);
        atomicAdd(&counts[e1], 1);
    }
}

// ---------------------------------------------------------------------------
// Kernel 2: bucket assignments by expert. Single block.
// ---------------------------------------------------------------------------
__global__ __launch_bounds__(256)
void scatter_kernel(const int* __restrict__ counts,
                    int* __restrict__ offsets,
                    const int* __restrict__ topk_idx,
                    const float* __restrict__ topk_w,
                    int* __restrict__ row_token,
                    float* __restrict__ row_w) {
    __shared__ int base[E_NUM];
    __shared__ int fill[E_NUM];
    const int tid = threadIdx.x;
    if (tid == 0) {
        int run = 0;
        for (int e = 0; e < E_NUM; e++) {
            offsets[e] = run;
            base[e] = run;
            run += counts[e];
        }
        offsets[E_NUM] = run;  // == N_ASSIGN
    }
    if (tid < E_NUM) fill[tid] = 0;
    __syncthreads();
    for (int a = tid; a < N_ASSIGN; a += blockDim.x) {
        const int e = topk_idx[a];
        const int pos = atomicAdd(&fill[e], 1);
        const int dst = base[e] + pos;
        row_token[dst] = a >> 1;
        row_w[dst] = topk_w[a];
    }
}

// ---------------------------------------------------------------------------
// Kernel 3: grouped gate/up GEMM + SiLU + combine weight -> h1 (fp32)
// Tile: 32 rows x 64 I-cols, K-chunk 32 over H. 256 threads.
// ---------------------------------------------------------------------------
#define C_TT 32
#define C_TI 64
#define C_KH 32

__global__ __launch_bounds__(256)
void gateup_kernel(const float* __restrict__ x,
                   const float* __restrict__ wg,
                   const float* __restrict__ wu,
                   const int* __restrict__ offsets,
                   const int* __restrict__ row_token,
                   const float* __restrict__ row_w,
                   float* __restrict__ h1) {
    const int e  = blockIdx.z;
    const int tt = blockIdx.y;
    const int it = blockIdx.x;
    const int beg = offsets[e];
    const int n   = offsets[e + 1] - beg;
    if (tt * C_TT >= n) return;

    __shared__ float Xs[C_TT][C_KH + 4];   // +4 keeps float4 alignment
    __shared__ float Wgs[C_KH][C_TI];
    __shared__ float Wus[C_KH][C_TI];
    __shared__ int   toks[C_TT];
    __shared__ float wts[C_TT];

    const int tid = threadIdx.x;
    if (tid < C_TT) {
        const int rl = tt * C_TT + tid;
        const int rc = (rl < n) ? rl : (n - 1);
        toks[tid] = row_token[beg + rc];
        wts[tid]  = (rl < n) ? row_w[beg + rl] : 0.f;
    }
    __syncthreads();

    const int ty = tid >> 4;  // 0..15 -> rows {2ty, 2ty+1}
    const int tx = tid & 15;  // 0..15 -> cols tx*4..tx*4+3
    const int i0 = it * C_TI;

    float accg[2][4], accu[2][4];
#pragma unroll
    for (int r = 0; r < 2; r++)
#pragma unroll
        for (int c = 0; c < 4; c++) { accg[r][c] = 0.f; accu[r][c] = 0.f; }

    const float* wgB = wg + (size_t)e * H_DIM * I_DIM + i0;
    const float* wuB = wu + (size_t)e * H_DIM * I_DIM + i0;

    // staging index precompute
    const int xr  = tid >> 3;        // X row 0..31
    const int xc4 = tid & 7;         // X float4 col 0..7
    const int wc4 = tid & 15;        // W float4 col 0..15
    const int wh  = tid >> 4;        // W h-row base 0..15

    for (int k0 = 0; k0 < H_DIM; k0 += C_KH) {
        // X tile 32x32: one float4 per thread (gathered rows, coalesced in h)
        {
            const float4 v = *((const float4*)(x + (size_t)toks[xr] * H_DIM + k0) + xc4);
            ((float4*)&Xs[xr][0])[xc4] = v;
        }
        // Wg/Wu tiles 32x64: two float4 per thread each
#pragma unroll
        for (int j = 0; j < 2; j++) {
            const int hr = wh + j * 16;
            const float4 g = *((const float4*)(wgB + (size_t)(k0 + hr) * I_DIM) + wc4);
            const float4 u = *((const float4*)(wuB + (size_t)(k0 + hr) * I_DIM) + wc4);
            ((float4*)&Wgs[hr][0])[wc4] = g;
            ((float4*)&Wus[hr][0])[wc4] = u;
        }
        __syncthreads();

#pragma unroll
        for (int hh = 0; hh < C_KH; hh++) {
            const float x0 = Xs[ty * 2 + 0][hh];
            const float x1 = Xs[ty * 2 + 1][hh];
            const float4 g4 = ((const float4*)&Wgs[hh][0])[tx];
            const float4 u4 = ((const float4*)&Wus[hh][0])[tx];
            accg[0][0] += x0 * g4.x; accg[0][1] += x0 * g4.y;
            accg[0][2] += x0 * g4.z; accg[0][3] += x0 * g4.w;
            accg[1][0] += x1 * g4.x; accg[1][1] += x1 * g4.y;
            accg[1][2] += x1 * g4.z; accg[1][3] += x1 * g4.w;
            accu[0][0] += x0 * u4.x; accu[0][1] += x0 * u4.y;
            accu[0][2] += x0 * u4.z; accu[0][3] += x0 * u4.w;
            accu[1][0] += x1 * u4.x; accu[1][1] += x1 * u4.y;
            accu[1][2] += x1 * u4.z; accu[1][3] += x1 * u4.w;
        }
        __syncthreads();
    }

    // epilogue: silu(gate)*up*combine_w -> h1 (float4 store)
#pragma unroll
    for (int r = 0; r < 2; r++) {
        const int rl = tt * C_TT + ty * 2 + r;
        if (rl < n) {
            const float w = wts[ty * 2 + r];
            float4 out;
            float* o = &out.x;
#pragma unroll
            for (int c = 0; c < 4; c++) {
                const float g = accg[r][c];
                const float s = g / (1.f + __expf(-g));   // silu
                o[c] = s * accu[r][c] * w;
            }
            *((float4*)(h1 + (size_t)(beg + rl) * I_DIM + i0) + tx) = out;
        }
    }
}

// ---------------------------------------------------------------------------
// Kernel 4: grouped down GEMM, atomicAdd scatter into y.
// Tile: 32 rows x 64 H-cols, K-chunk 32 over I. 256 threads.
// ---------------------------------------------------------------------------
#define D_TT 32
#define D_TH 64
#define D_KI 32

__global__ __launch_bounds__(256)
void down_kernel(const float* __restrict__ h1,
                 const float* __restrict__ wd,
                 const int* __restrict__ offsets,
                 const int* __restrict__ row_token,
                 float* __restrict__ y) {
    const int e  = blockIdx.z;
    const int tt = blockIdx.y;
    const int ht = blockIdx.x;
    const int beg = offsets[e];
    const int n   = offsets[e + 1] - beg;
    if (tt * D_TT >= n) return;

    __shared__ float Hs[D_TT][D_KI + 4];
    __shared__ float Wds[D_KI][D_TH];
    __shared__ int   toks[D_TT];

    const int tid = threadIdx.x;
    if (tid < D_TT) {
        const int rl = tt * D_TT + tid;
        toks[tid] = (rl < n) ? row_token[beg + rl] : -1;
    }
    __syncthreads();

    const int ty = tid >> 4;
    const int tx = tid & 15;
    const int h0 = ht * D_TH;

    float acc[2][4];
#pragma unroll
    for (int r = 0; r < 2; r++)
#pragma unroll
        for (int c = 0; c < 4; c++) acc[r][c] = 0.f;

    const float* wdB = wd + (size_t)e * I_DIM * H_DIM + h0;

    const int xr  = tid >> 3;
    const int xc4 = tid & 7;
    const int wc4 = tid & 15;
    const int wh  = tid >> 4;

    for (int k0 = 0; k0 < I_DIM; k0 += D_KI) {
        // h1 tile 32x32 (rows contiguous within expert -> fully coalesced)
        {
            const int rl = tt * D_TT + xr;
            const int rc = (rl < n) ? rl : (n - 1);
            const float4 v = *((const float4*)(h1 + (size_t)(beg + rc) * I_DIM + k0) + xc4);
            ((float4*)&Hs[xr][0])[xc4] = v;
        }
        // wd tile 32x64
#pragma unroll
        for (int j = 0; j < 2; j++) {
            const int ir = wh + j * 16;
            const float4 v = *((const float4*)(wdB + (size_t)(k0 + ir) * H_DIM) + wc4);
            ((float4*)&Wds[ir][0])[wc4] = v;
        }
        __syncthreads();

#pragma unroll
        for (int ii = 0; ii < D_KI; ii++) {
            const float x0 = Hs[ty * 2 + 0][ii];
            const float x1 = Hs[ty * 2 + 1][ii];
            const float4 w4 = ((const float4*)&Wds[ii][0])[tx];
            acc[0][0] += x0 * w4.x; acc[0][1] += x0 * w4.y;
            acc[0][2] += x0 * w4.z; acc[0][3] += x0 * w4.w;
            acc[1][0] += x1 * w4.x; acc[1][1] += x1 * w4.y;
            acc[1][2] += x1 * w4.z; acc[1][3] += x1 * w4.w;
        }
        __syncthreads();
    }

#pragma unroll
    for (int r = 0; r < 2; r++) {
        const int rl = tt * D_TT + ty * 2 + r;
        if (rl < n) {
            const int t = toks[ty * 2 + r];
            float* yp = y + (size_t)t * H_DIM + h0 + tx * 4;
#pragma unroll
            for (int c = 0; c < 4; c++) atomicAdd(yp + c, acc[r][c]);
        }
    }
}

// ---------------------------------------------------------------------------
extern "C" void kernel_launch(void* const* d_in, const int* in_sizes, int n_in,
                              void* d_out, int out_size, void* d_ws, size_t ws_size,
                              hipStream_t stream) {
    const float* x  = (const float*)d_in[0];   // [T,H]
    const float* wr = (const float*)d_in[1];   // [H,E]
    const float* wg = (const float*)d_in[2];   // [E,H,I]
    const float* wu = (const float*)d_in[3];   // [E,H,I]
    const float* wd = (const float*)d_in[4];   // [E,I,H]
    float* y = (float*)d_out;                  // [T,H]

    char* ws = (char*)d_ws;
    int*   counts    = (int*)(ws + WS_OFF_COUNTS);
    int*   offsets   = (int*)(ws + WS_OFF_OFFSETS);
    int*   topk_idx  = (int*)(ws + WS_OFF_TOPKIDX);
    float* topk_w    = (float*)(ws + WS_OFF_TOPKW);
    int*   row_token = (int*)(ws + WS_OFF_ROWTOK);
    float* row_w     = (float*)(ws + WS_OFF_ROWW);
    float* h1        = (float*)(ws + WS_OFF_H1);   // [4096, I]

    hipMemsetAsync(counts, 0, 64, stream);
    hipMemsetAsync(y, 0, (size_t)T_TOK * H_DIM * sizeof(float), stream);

    router_kernel<<<T_TOK, 64, 0, stream>>>(x, wr, counts, topk_idx, topk_w);
    scatter_kernel<<<1, 256, 0, stream>>>(counts, offsets, topk_idx, topk_w,
                                          row_token, row_w);
    gateup_kernel<<<dim3(I_DIM / C_TI, T_TOK / C_TT, E_NUM), 256, 0, stream>>>(
        x, wg, wu, offsets, row_token, row_w, h1);
    down_kernel<<<dim3(H_DIM / D_TH, T_TOK / D_TT, E_NUM), 256, 0, stream>>>(
        h1, wd, offsets, row_token, y);
}

// Round 2
// 777.672 us; speedup vs baseline: 1.4804x; 1.4804x over previous
//
#include <hip/hip_runtime.h>
#include <hip/hip_bf16.h>
#include <math.h>

// MoE top-2 SwiGLU, grouped-by-expert, bf16 MFMA execution.
// T=2048, H=1024, I=2048, E=16, K=2.
//
// Pipeline:
//   1) router_kernel : logits -> top-2 -> renorm weights
//   2) scatter_kernel: bucket assignments by expert (row lists + inverse map)
//   3) gather_x      : Xg[row] = bf16(x[token])   (A rows contiguous/bf16)
//   4) gemm_gu       : g/u = Xg_e @ W{g,u}_e  (MFMA 16x16x32 bf16, BM=256
//                      per-expert so fp32 weights stream from HBM ~once,
//                      converted to bf16 in-register during LDS staging)
//   5) act_kernel    : h1 = bf16(silu(g)*u*row_w)  (in-place over g)
//   6) gemm_down     : yp[row] = h1_e @ wd_e  (fp32 out, no atomics)
//   7) combine_kernel: y[t] = yp[row0] + yp[row1]

#define T_TOK 2048
#define H_DIM 1024
#define I_DIM 2048
#define E_NUM 16
#define N_ASSIGN 4096

typedef __attribute__((ext_vector_type(8))) short short8;
typedef __attribute__((ext_vector_type(4))) float floatx4;

// ---------------- workspace layout (bytes) ----------------
#define WS_OFF_COUNTS   0
#define WS_OFF_OFFSETS  64                       // int[17]
#define WS_OFF_TOPKIDX  256                      // int[4096]
#define WS_OFF_TOPKW    (WS_OFF_TOPKIDX + 16384) // float[4096]
#define WS_OFF_ROWTOK   (WS_OFF_TOPKW  + 16384)  // int[4096]
#define WS_OFF_ROWW     (WS_OFF_ROWTOK + 16384)  // float[4096]
#define WS_OFF_ASSROW   (WS_OFF_ROWW   + 16384)  // int[4096]
#define WS_OFF_XG       (128 * 1024)                       // bf16 [4096][1024]  8 MB
#define WS_OFF_G        (WS_OFF_XG + 8u  * 1024 * 1024)    // bf16 [4096][2048] 16 MB (h1 aliases)
#define WS_OFF_U        (WS_OFF_G  + 16u * 1024 * 1024)    // bf16 [4096][2048] 16 MB (yp aliases)
// total ~40.1 MB

// ---------------- bf16 helpers (RNE, branch-free) ----------------
__device__ __forceinline__ ushort f2bf(float f) {
    union { float f; unsigned int u; } v; v.f = f;
    unsigned int r = (v.u + 0x7fffu + ((v.u >> 16) & 1u)) >> 16;
    return (ushort)r;
}
__device__ __forceinline__ float bf2f(ushort h) {
    union { unsigned int u; float f; } v; v.u = (unsigned int)h << 16;
    return v.f;
}

// ---------------------------------------------------------------------------
// Kernel 1: router. One wave per token.
// ---------------------------------------------------------------------------
__global__ __launch_bounds__(64)
void router_kernel(const float* __restrict__ x,
                   const float* __restrict__ wr,
                   int* __restrict__ counts,
                   int* __restrict__ topk_idx,
                   float* __restrict__ topk_w) {
    const int t = blockIdx.x;
    const int lane = threadIdx.x;
    const float* xt = x + (size_t)t * H_DIM;

    float acc[E_NUM];
#pragma unroll
    for (int e = 0; e < E_NUM; e++) acc[e] = 0.f;

    for (int h = lane; h < H_DIM; h += 64) {
        const float xv = xt[h];
        const float* wrow = wr + h * E_NUM;
#pragma unroll
        for (int e = 0; e < E_NUM; e++) acc[e] += xv * wrow[e];
    }
#pragma unroll
    for (int off = 32; off > 0; off >>= 1) {
#pragma unroll
        for (int e = 0; e < E_NUM; e++)
            acc[e] += __shfl_down(acc[e], off);
    }
    if (lane == 0) {
        int e0 = 0; float l0 = acc[0];
        for (int e = 1; e < E_NUM; e++)
            if (acc[e] > l0) { l0 = acc[e]; e0 = e; }
        int e1 = (e0 == 0) ? 1 : 0;
        float l1 = acc[e1];
        for (int e = 0; e < E_NUM; e++)
            if (e != e0 && acc[e] > l1) { l1 = acc[e]; e1 = e; }
        const float w0 = 1.f / (1.f + __expf(l1 - l0));  // renorm == softmax over top-2
        const float w1 = 1.f - w0;
        topk_idx[t * 2 + 0] = e0;
        topk_idx[t * 2 + 1] = e1;
        topk_w[t * 2 + 0] = w0;
        topk_w[t * 2 + 1] = w1;
        atomicAdd(&counts[e0], 1);
        atomicAdd(&counts[e1], 1);
    }
}

// ---------------------------------------------------------------------------
// Kernel 2: bucket assignments by expert; also inverse map assign->row.
// ---------------------------------------------------------------------------
__global__ __launch_bounds__(256)
void scatter_kernel(const int* __restrict__ counts,
                    int* __restrict__ offsets,
                    const int* __restrict__ topk_idx,
                    const float* __restrict__ topk_w,
                    int* __restrict__ row_token,
                    float* __restrict__ row_w,
                    int* __restrict__ assign_row) {
    __shared__ int base[E_NUM];
    __shared__ int fill[E_NUM];
    const int tid = threadIdx.x;
    if (tid == 0) {
        int run = 0;
        for (int e = 0; e < E_NUM; e++) {
            offsets[e] = run;
            base[e] = run;
            run += counts[e];
        }
        offsets[E_NUM] = run;
    }
    if (tid < E_NUM) fill[tid] = 0;
    __syncthreads();
    for (int a = tid; a < N_ASSIGN; a += blockDim.x) {
        const int e = topk_idx[a];
        const int pos = atomicAdd(&fill[e], 1);
        const int dst = base[e] + pos;
        row_token[dst] = a >> 1;
        row_w[dst] = topk_w[a];
        assign_row[a] = dst;
    }
}

// ---------------------------------------------------------------------------
// Kernel 3: gather x rows into expert-grouped bf16 matrix Xg[4096][1024].
// ---------------------------------------------------------------------------
__global__ __launch_bounds__(256)
void gather_x_kernel(const float* __restrict__ x,
                     const int* __restrict__ row_token,
                     ushort* __restrict__ Xg) {
    const int r = blockIdx.x;
    const int t = row_token[r];
    const int c = threadIdx.x;                       // one float4 per thread
    floatx4 v = ((const floatx4*)(x + (size_t)t * H_DIM))[c];
    ushort4 o;
    o.x = f2bf(v[0]); o.y = f2bf(v[1]); o.z = f2bf(v[2]); o.w = f2bf(v[3]);
    ((ushort4*)(Xg + (size_t)r * H_DIM))[c] = o;
}

// ---------------------------------------------------------------------------
// Grouped GEMM body. C[m][n] = sum_k A[m][k]*B[k][n] for one expert's rows.
//   A: bf16 [4096][KD] rows (expert rows contiguous at beg)
//   B: fp32 [KD][NT]  (this expert's weight), converted bf16 during staging
// Tile: BM=256 (4 waves x 64 rows), BN=64, BK=32; MFMA 16x16x32 bf16.
// LDS A: frag-ordered [kquad][256 rows][8 bf16] -> conflict-free b128 reads,
//        contiguous global_load_lds dests (wave w stages kquad w).
// LDS B: transposed [n][k], row stride 40 bf16 -> staging b32 writes hit all
//        32 banks (lanes: 16 kh x 4 n4 -> banks (20n+kh)%32 all distinct),
//        b128 frag reads ~2-way (free).
// ---------------------------------------------------------------------------
template<int KD, int NT, bool OBF>
__device__ __forceinline__ void gemm_body(const ushort* __restrict__ A,
                                          const float* __restrict__ B,
                                          void* __restrict__ C,
                                          int beg, int n, int mtile, int ntile) {
    __shared__ ushort As[4 * 256 * 8];   // 16 KB
    __shared__ ushort Bs[64 * 40];       //  5 KB

    const int tid  = threadIdx.x;
    const int lane = tid & 63;
    const int w    = tid >> 6;       // wave 0..3
    const int ml   = lane & 15;
    const int q    = lane >> 4;      // k-quad

    floatx4 acc[4][4];
#pragma unroll
    for (int i = 0; i < 4; i++)
#pragma unroll
        for (int j = 0; j < 4; j++) acc[i][j] = (floatx4){0.f, 0.f, 0.f, 0.f};

    // A staging: wave w stages k-quad w (8 bf16), rows j*64+lane.
    const ushort* Ap[4];
#pragma unroll
    for (int j = 0; j < 4; j++) {
        int row = beg + mtile * 256 + j * 64 + lane;
        row = row < 4095 ? row : 4095;              // clamp padding rows in-bounds
        Ap[j] = A + (size_t)row * KD + w * 8;
    }
    ushort* AsW = &As[w * 2048];

    // B staging: thread (kh = tid&15, n4 = tid>>4) covers k in {2kh,2kh+1},
    // n in {4*n4 .. 4*n4+3}.
    const int kh = tid & 15;
    const int n4 = tid >> 4;
    const float* Bp = B + (size_t)(ntile * 64 + n4 * 4);

    for (int k0 = 0; k0 < KD; k0 += 32) {
        // ---- A tile: 16 global_load_lds dwordx4 (4 per wave) ----
#pragma unroll
        for (int j = 0; j < 4; j++)
            __builtin_amdgcn_global_load_lds(
                (const __attribute__((address_space(1))) unsigned int*)(Ap[j] + k0),
                (__attribute__((address_space(3))) unsigned int*)(AsW + j * 512),
                16, 0, 0);

        // ---- B tile: fp32 load -> bf16 -> transposed LDS write ----
        const float* bsrc = Bp + (size_t)(k0 + 2 * kh) * NT;
        floatx4 b0 = *(const floatx4*)bsrc;
        floatx4 b1 = *(const floatx4*)(bsrc + NT);
#pragma unroll
        for (int j2 = 0; j2 < 4; j2++) {
            unsigned int p = (unsigned int)f2bf(b0[j2]) |
                             ((unsigned int)f2bf(b1[j2]) << 16);
            *(unsigned int*)&Bs[(n4 * 4 + j2) * 40 + 2 * kh] = p;
        }
        __syncthreads();

        // ---- fragments + MFMA ----
        short8 af[4], bfr[4];
#pragma unroll
        for (int mt = 0; mt < 4; mt++)
            af[mt] = *(const short8*)&As[q * 2048 + (w * 64 + mt * 16 + ml) * 8];
#pragma unroll
        for (int nt = 0; nt < 4; nt++)
            bfr[nt] = *(const short8*)&Bs[(nt * 16 + ml) * 40 + q * 8];
#pragma unroll
        for (int mt = 0; mt < 4; mt++)
#pragma unroll
            for (int nt = 0; nt < 4; nt++)
                acc[mt][nt] = __builtin_amdgcn_mfma_f32_16x16x32_bf16(
                    af[mt], bfr[nt], acc[mt][nt], 0, 0, 0);
        __syncthreads();
    }

    // ---- epilogue: C/D layout col=lane&15, row=(lane>>4)*4+reg ----
#pragma unroll
    for (int mt = 0; mt < 4; mt++) {
#pragma unroll
        for (int nt = 0; nt < 4; nt++) {
#pragma unroll
            for (int r = 0; r < 4; r++) {
                const int rl = mtile * 256 + w * 64 + mt * 16 + q * 4 + r;
                if (rl < n) {
                    const size_t off = (size_t)(beg + rl) * NT + ntile * 64 + nt * 16 + ml;
                    if (OBF) ((ushort*)C)[off] = f2bf(acc[mt][nt][r]);
                    else     ((float*)C)[off]  = acc[mt][nt][r];
                }
            }
        }
    }
}

__global__ __launch_bounds__(256)
void gemm_gu_kernel(const ushort* __restrict__ Xg,
                    const float* __restrict__ wg,
                    const float* __restrict__ wu,
                    const int* __restrict__ offsets,
                    ushort* __restrict__ gbuf,
                    ushort* __restrict__ ubuf) {
    const int z = blockIdx.z;           // e*2 + which
    const int e = z >> 1;
    const int beg = offsets[e];
    const int n = offsets[e + 1] - beg;
    const int mtile = blockIdx.y;
    if (mtile * 256 >= n) return;
    const float* B = ((z & 1) ? wu : wg) + (size_t)e * H_DIM * I_DIM;
    ushort* C = (z & 1) ? ubuf : gbuf;
    gemm_body<H_DIM, I_DIM, true>(Xg, B, C, beg, n, mtile, blockIdx.x);
}

__global__ __launch_bounds__(256)
void gemm_down_kernel(const ushort* __restrict__ h1,
                      const float* __restrict__ wd,
                      const int* __restrict__ offsets,
                      float* __restrict__ yp) {
    const int e = blockIdx.z;
    const int beg = offsets[e];
    const int n = offsets[e + 1] - beg;
    const int mtile = blockIdx.y;
    if (mtile * 256 >= n) return;
    gemm_body<I_DIM, H_DIM, false>(h1, wd + (size_t)e * I_DIM * H_DIM, yp,
                                   beg, n, mtile, blockIdx.x);
}

// ---------------------------------------------------------------------------
// Kernel 5: h1 = bf16(silu(g) * u * row_w), in place over g.
// ---------------------------------------------------------------------------
__global__ __launch_bounds__(256)
void act_kernel(ushort* __restrict__ g, const ushort* __restrict__ u,
                const float* __restrict__ row_w) {
    const int r = blockIdx.x;
    const float wgt = row_w[r];
    ushort* gp = g + (size_t)r * I_DIM + threadIdx.x * 8;
    const ushort* up = u + (size_t)r * I_DIM + threadIdx.x * 8;
    short8 g8 = *(const short8*)gp;
    short8 u8 = *(const short8*)up;
    short8 o;
#pragma unroll
    for (int i = 0; i < 8; i++) {
        const float gv = bf2f((ushort)g8[i]);
        const float uv = bf2f((ushort)u8[i]);
        const float s = gv / (1.f + __expf(-gv));
        o[i] = (short)f2bf(s * uv * wgt);
    }
    *(short8*)gp = o;
}

// ---------------------------------------------------------------------------
// Kernel 7: y[t] = yp[row0] + yp[row1]
// ---------------------------------------------------------------------------
__global__ __launch_bounds__(256)
void combine_kernel(const float* __restrict__ yp,
                    const int* __restrict__ assign_row,
                    float* __restrict__ y) {
    const int t = blockIdx.x;
    const int r0 = assign_row[t * 2];
    const int r1 = assign_row[t * 2 + 1];
    const int c = threadIdx.x;                      // one float4 per thread
    floatx4 a = ((const floatx4*)(yp + (size_t)r0 * H_DIM))[c];
    floatx4 b = ((const floatx4*)(yp + (size_t)r1 * H_DIM))[c];
    ((floatx4*)(y + (size_t)t * H_DIM))[c] = a + b;
}

// ---------------------------------------------------------------------------
extern "C" void kernel_launch(void* const* d_in, const int* in_sizes, int n_in,
                              void* d_out, int out_size, void* d_ws, size_t ws_size,
                              hipStream_t stream) {
    const float* x  = (const float*)d_in[0];
    const float* wr = (const float*)d_in[1];
    const float* wg = (const float*)d_in[2];
    const float* wu = (const float*)d_in[3];
    const float* wd = (const float*)d_in[4];
    float* y = (float*)d_out;

    char* ws = (char*)d_ws;
    int*    counts     = (int*)(ws + WS_OFF_COUNTS);
    int*    offsets    = (int*)(ws + WS_OFF_OFFSETS);
    int*    topk_idx   = (int*)(ws + WS_OFF_TOPKIDX);
    float*  topk_w     = (float*)(ws + WS_OFF_TOPKW);
    int*    row_token  = (int*)(ws + WS_OFF_ROWTOK);
    float*  row_w      = (float*)(ws + WS_OFF_ROWW);
    int*    assign_row = (int*)(ws + WS_OFF_ASSROW);
    ushort* Xg         = (ushort*)(ws + WS_OFF_XG);
    ushort* gbuf       = (ushort*)(ws + WS_OFF_G);   // h1 aliases after act
    ushort* ubuf       = (ushort*)(ws + WS_OFF_U);
    float*  yp         = (float*)(ws + WS_OFF_U);    // aliases ubuf (u consumed)

    hipMemsetAsync(counts, 0, 64, stream);

    router_kernel<<<T_TOK, 64, 0, stream>>>(x, wr, counts, topk_idx, topk_w);
    scatter_kernel<<<1, 256, 0, stream>>>(counts, offsets, topk_idx, topk_w,
                                          row_token, row_w, assign_row);
    gather_x_kernel<<<N_ASSIGN, 256, 0, stream>>>(x, row_token, Xg);
    gemm_gu_kernel<<<dim3(I_DIM / 64, 16, E_NUM * 2), 256, 0, stream>>>(
        Xg, wg, wu, offsets, gbuf, ubuf);
    act_kernel<<<N_ASSIGN, 256, 0, stream>>>(gbuf, ubuf, row_w);
    gemm_down_kernel<<<dim3(H_DIM / 64, 16, E_NUM), 256, 0, stream>>>(
        gbuf, wd, offsets, yp);
    combine_kernel<<<T_TOK, 256, 0, stream>>>(yp, assign_row, y);
}

// Round 3
// 561.879 us; speedup vs baseline: 2.0489x; 1.3841x over previous
//
#include <hip/hip_runtime.h>
#include <hip/hip_bf16.h>
#include <math.h>

// MoE top-2 SwiGLU, grouped-by-expert, bf16 MFMA.
// T=2048, H=1024, I=2048, E=16, K=2.
//
// Round 3: fix latency-starvation (round-2: 1 block/CU, MfmaUtil 3.8%).
//   - BM=128 + tile map -> ~1024 active blocks per GEMM (4/CU)
//   - down GEMM split-K=2, partials atomicAdd'ed into y (no yp/combine pass)
//   - row-major LDS A tile: global_load_lds lanes cover contiguous 64B lines
//   - gate+up fused in one block (shared A), silu*up*w epilogue -> h1 bf16

#define T_TOK 2048
#define H_DIM 1024
#define I_DIM 2048
#define E_NUM 16
#define N_ASSIGN 4096
#define BM 128
#define TILE_MAX 48   // max sum of ceil(n_e/BM) = 4096/128 + 16

typedef __attribute__((ext_vector_type(8))) short short8;
typedef __attribute__((ext_vector_type(4))) float floatx4;

// ---------------- workspace layout (bytes) ----------------
#define WS_OFF_COUNTS   0
#define WS_OFF_OFFSETS  64                        // int[17]
#define WS_OFF_TOPKIDX  256                       // int[4096]
#define WS_OFF_TOPKW    (WS_OFF_TOPKIDX + 16384)  // float[4096]
#define WS_OFF_ROWTOK   (WS_OFF_TOPKW  + 16384)   // int[4096]
#define WS_OFF_ROWW     (WS_OFF_ROWTOK + 16384)   // float[4096]
#define WS_OFF_TILEE    (WS_OFF_ROWW   + 16384)   // int[64]
#define WS_OFF_TILEM    (WS_OFF_TILEE  + 256)     // int[64]
#define WS_OFF_TILEC    (WS_OFF_TILEM  + 256)     // int[1]
#define WS_OFF_XG       (128 * 1024)                      // bf16 [4096][1024]  8 MB
#define WS_OFF_H1       (WS_OFF_XG + 8u * 1024 * 1024)    // bf16 [4096][2048] 16 MB
// total ~24.1 MB (round 2 proved >=40 MB available)

// ---------------- bf16 helpers (RNE) ----------------
__device__ __forceinline__ ushort f2bf(float f) {
    union { float f; unsigned int u; } v; v.f = f;
    unsigned int r = (v.u + 0x7fffu + ((v.u >> 16) & 1u)) >> 16;
    return (ushort)r;
}

// ---------------------------------------------------------------------------
// Kernel 1: router. One wave per token.
// ---------------------------------------------------------------------------
__global__ __launch_bounds__(64)
void router_kernel(const float* __restrict__ x,
                   const float* __restrict__ wr,
                   int* __restrict__ counts,
                   int* __restrict__ topk_idx,
                   float* __restrict__ topk_w) {
    const int t = blockIdx.x;
    const int lane = threadIdx.x;
    const float* xt = x + (size_t)t * H_DIM;

    float acc[E_NUM];
#pragma unroll
    for (int e = 0; e < E_NUM; e++) acc[e] = 0.f;

    for (int h = lane; h < H_DIM; h += 64) {
        const float xv = xt[h];
        const float* wrow = wr + h * E_NUM;
#pragma unroll
        for (int e = 0; e < E_NUM; e++) acc[e] += xv * wrow[e];
    }
#pragma unroll
    for (int off = 32; off > 0; off >>= 1) {
#pragma unroll
        for (int e = 0; e < E_NUM; e++)
            acc[e] += __shfl_down(acc[e], off);
    }
    if (lane == 0) {
        int e0 = 0; float l0 = acc[0];
        for (int e = 1; e < E_NUM; e++)
            if (acc[e] > l0) { l0 = acc[e]; e0 = e; }
        int e1 = (e0 == 0) ? 1 : 0;
        float l1 = acc[e1];
        for (int e = 0; e < E_NUM; e++)
            if (e != e0 && acc[e] > l1) { l1 = acc[e]; e1 = e; }
        const float w0 = 1.f / (1.f + __expf(l1 - l0));  // renorm == softmax over top-2
        const float w1 = 1.f - w0;
        topk_idx[t * 2 + 0] = e0;
        topk_idx[t * 2 + 1] = e1;
        topk_w[t * 2 + 0] = w0;
        topk_w[t * 2 + 1] = w1;
        atomicAdd(&counts[e0], 1);
        atomicAdd(&counts[e1], 1);
    }
}

// ---------------------------------------------------------------------------
// Kernel 2: bucket assignments by expert + build (expert, mtile) tile map.
// ---------------------------------------------------------------------------
__global__ __launch_bounds__(256)
void scatter_kernel(const int* __restrict__ counts,
                    int* __restrict__ offsets,
                    const int* __restrict__ topk_idx,
                    const float* __restrict__ topk_w,
                    int* __restrict__ row_token,
                    float* __restrict__ row_w,
                    int* __restrict__ tile_e,
                    int* __restrict__ tile_m,
                    int* __restrict__ tile_c) {
    __shared__ int base[E_NUM];
    __shared__ int fill[E_NUM];
    const int tid = threadIdx.x;
    if (tid == 0) {
        int run = 0, tc = 0;
        for (int e = 0; e < E_NUM; e++) {
            offsets[e] = run;
            base[e] = run;
            const int cnt = counts[e];
            run += cnt;
            for (int m = 0; m * BM < cnt; m++) {
                tile_e[tc] = e;
                tile_m[tc] = m;
                tc++;
            }
        }
        offsets[E_NUM] = run;
        *tile_c = tc;
    }
    if (tid < E_NUM) fill[tid] = 0;
    __syncthreads();
    for (int a = tid; a < N_ASSIGN; a += blockDim.x) {
        const int e = topk_idx[a];
        const int pos = atomicAdd(&fill[e], 1);
        const int dst = base[e] + pos;
        row_token[dst] = a >> 1;
        row_w[dst] = topk_w[a];
    }
}

// ---------------------------------------------------------------------------
// Kernel 3: gather x rows into expert-grouped bf16 matrix Xg[4096][1024].
// ---------------------------------------------------------------------------
__global__ __launch_bounds__(256)
void gather_x_kernel(const float* __restrict__ x,
                     const int* __restrict__ row_token,
                     ushort* __restrict__ Xg) {
    const int r = blockIdx.x;
    const int t = row_token[r];
    const int c = threadIdx.x;
    floatx4 v = ((const floatx4*)(x + (size_t)t * H_DIM))[c];
    ushort4 o;
    o.x = f2bf(v[0]); o.y = f2bf(v[1]); o.z = f2bf(v[2]); o.w = f2bf(v[3]);
    ((ushort4*)(Xg + (size_t)r * H_DIM))[c] = o;
}

// ---------------------------------------------------------------------------
// Kernel 4: fused gate+up grouped GEMM + SwiGLU epilogue -> h1 bf16.
// Tile: BM=128 rows x BN=64 cols (per matrix), BK=32. 4 waves; wave w owns
// rows [32w,32w+32) (stages AND consumes them), both gate & up cols.
// LDS A row-major [128][32] bf16: global_load_lds lane groups of 4 cover
// contiguous 64B lines. LDS B transposed [n][k] stride 40 (round-2-verified).
// ---------------------------------------------------------------------------
__global__ __launch_bounds__(256)
void gemm_gu_kernel(const ushort* __restrict__ Xg,
                    const float* __restrict__ wg,
                    const float* __restrict__ wu,
                    const int* __restrict__ offsets,
                    const float* __restrict__ row_w,
                    const int* __restrict__ tile_e,
                    const int* __restrict__ tile_m,
                    const int* __restrict__ tile_c,
                    ushort* __restrict__ h1) {
    if ((int)blockIdx.y >= *tile_c) return;
    const int e     = tile_e[blockIdx.y];
    const int mtile = tile_m[blockIdx.y];
    const int ntile = blockIdx.x;           // 0..31 (I/64)
    const int beg = offsets[e];
    const int n   = offsets[e + 1] - beg;

    __shared__ ushort As[BM * 32];          // row-major, row stride 32 ush
    __shared__ ushort Bgs[64 * 40];
    __shared__ ushort Bus[64 * 40];
    __shared__ float  wts[BM];

    const int tid  = threadIdx.x;
    const int lane = tid & 63;
    const int w    = tid >> 6;
    const int ml   = lane & 15;
    const int q    = lane >> 4;

    if (tid < BM) {
        const int rl = mtile * BM + tid;
        wts[tid] = (rl < n) ? row_w[beg + rl] : 0.f;
    }

    floatx4 accg[2][4], accu[2][4];
#pragma unroll
    for (int i = 0; i < 2; i++)
#pragma unroll
        for (int j = 0; j < 4; j++) {
            accg[i][j] = (floatx4){0.f, 0.f, 0.f, 0.f};
            accu[i][j] = (floatx4){0.f, 0.f, 0.f, 0.f};
        }

    // A staging: wave w, instr j covers rows 32w+16j .. +16 (lane>>2 = row-in-16,
    // lane&3 = 16B quad within the row's 64B k-chunk)
    const ushort* Ap[2];
#pragma unroll
    for (int j = 0; j < 2; j++) {
        int row = beg + mtile * BM + 32 * w + 16 * j + (lane >> 2);
        row = row < 4095 ? row : 4095;
        Ap[j] = Xg + (size_t)row * H_DIM + (lane & 3) * 8;
    }

    // B staging: kh=tid&15 -> k pair {2kh,2kh+1}; n4=tid>>4 -> cols 4n4..4n4+3
    const int kh = tid & 15;
    const int n4 = tid >> 4;
    const float* Bgp = wg + (size_t)e * H_DIM * I_DIM + ntile * 64 + n4 * 4;
    const float* Bup = wu + (size_t)e * H_DIM * I_DIM + ntile * 64 + n4 * 4;

    for (int k0 = 0; k0 < H_DIM; k0 += 32) {
#pragma unroll
        for (int j = 0; j < 2; j++)
            __builtin_amdgcn_global_load_lds(
                (const __attribute__((address_space(1))) unsigned int*)(Ap[j] + k0),
                (__attribute__((address_space(3))) unsigned int*)(As + (32 * w + 16 * j) * 32),
                16, 0, 0);

        const size_t boff = (size_t)(k0 + 2 * kh) * I_DIM;
        floatx4 g0 = *(const floatx4*)(Bgp + boff);
        floatx4 g1 = *(const floatx4*)(Bgp + boff + I_DIM);
        floatx4 u0 = *(const floatx4*)(Bup + boff);
        floatx4 u1 = *(const floatx4*)(Bup + boff + I_DIM);
#pragma unroll
        for (int j2 = 0; j2 < 4; j2++) {
            unsigned int pg = (unsigned int)f2bf(g0[j2]) |
                              ((unsigned int)f2bf(g1[j2]) << 16);
            unsigned int pu = (unsigned int)f2bf(u0[j2]) |
                              ((unsigned int)f2bf(u1[j2]) << 16);
            *(unsigned int*)&Bgs[(n4 * 4 + j2) * 40 + 2 * kh] = pg;
            *(unsigned int*)&Bus[(n4 * 4 + j2) * 40 + 2 * kh] = pu;
        }
        __syncthreads();

        short8 af[2], bg[4], bu[4];
#pragma unroll
        for (int mt = 0; mt < 2; mt++)
            af[mt] = *(const short8*)&As[(32 * w + mt * 16 + ml) * 32 + q * 8];
#pragma unroll
        for (int nt = 0; nt < 4; nt++) {
            bg[nt] = *(const short8*)&Bgs[(nt * 16 + ml) * 40 + q * 8];
            bu[nt] = *(const short8*)&Bus[(nt * 16 + ml) * 40 + q * 8];
        }
#pragma unroll
        for (int mt = 0; mt < 2; mt++)
#pragma unroll
            for (int nt = 0; nt < 4; nt++) {
                accg[mt][nt] = __builtin_amdgcn_mfma_f32_16x16x32_bf16(
                    af[mt], bg[nt], accg[mt][nt], 0, 0, 0);
                accu[mt][nt] = __builtin_amdgcn_mfma_f32_16x16x32_bf16(
                    af[mt], bu[nt], accu[mt][nt], 0, 0, 0);
            }
        __syncthreads();
    }

    // epilogue: h1 = bf16(silu(g)*u*w). C/D: col=ml, row=q*4+r within tile.
#pragma unroll
    for (int mt = 0; mt < 2; mt++)
#pragma unroll
        for (int r = 0; r < 4; r++) {
            const int rloc = 32 * w + mt * 16 + q * 4 + r;
            const int rl = mtile * BM + rloc;
            if (rl < n) {
                const float cw = wts[rloc];
#pragma unroll
                for (int nt = 0; nt < 4; nt++) {
                    const float g = accg[mt][nt][r];
                    const float s = g / (1.f + __expf(-g));
                    h1[(size_t)(beg + rl) * I_DIM + ntile * 64 + nt * 16 + ml] =
                        f2bf(s * accu[mt][nt][r] * cw);
                }
            }
        }
}

// ---------------------------------------------------------------------------
// Kernel 5: down grouped GEMM, split-K=2, atomicAdd partials into y (zeroed).
// Tile: BM=128 x BN=64, BK=32 over K-half 1024. Same LDS scheme as gu.
// ---------------------------------------------------------------------------
__global__ __launch_bounds__(256)
void gemm_down_kernel(const ushort* __restrict__ h1,
                      const float* __restrict__ wd,
                      const int* __restrict__ offsets,
                      const int* __restrict__ row_token,
                      const int* __restrict__ tile_e,
                      const int* __restrict__ tile_m,
                      const int* __restrict__ tile_c,
                      float* __restrict__ y) {
    if ((int)blockIdx.y >= *tile_c) return;
    const int e     = tile_e[blockIdx.y];
    const int mtile = tile_m[blockIdx.y];
    const int ntile = blockIdx.x;           // 0..15 (H/64)
    const int kbase = blockIdx.z * 1024;    // split-K half
    const int beg = offsets[e];
    const int n   = offsets[e + 1] - beg;

    __shared__ ushort As[BM * 32];
    __shared__ ushort Bs[64 * 40];
    __shared__ int    toks[BM];

    const int tid  = threadIdx.x;
    const int lane = tid & 63;
    const int w    = tid >> 6;
    const int ml   = lane & 15;
    const int q    = lane >> 4;

    if (tid < BM) {
        const int rl = mtile * BM + tid;
        toks[tid] = (rl < n) ? row_token[beg + rl] : 0;
    }

    floatx4 acc[2][4];
#pragma unroll
    for (int i = 0; i < 2; i++)
#pragma unroll
        for (int j = 0; j < 4; j++) acc[i][j] = (floatx4){0.f, 0.f, 0.f, 0.f};

    const ushort* Ap[2];
#pragma unroll
    for (int j = 0; j < 2; j++) {
        int row = beg + mtile * BM + 32 * w + 16 * j + (lane >> 2);
        row = row < 4095 ? row : 4095;
        Ap[j] = h1 + (size_t)row * I_DIM + kbase + (lane & 3) * 8;
    }

    const int kh = tid & 15;
    const int n4 = tid >> 4;
    const float* Bp = wd + (size_t)e * I_DIM * H_DIM +
                      (size_t)kbase * H_DIM + ntile * 64 + n4 * 4;

    for (int k0 = 0; k0 < 1024; k0 += 32) {
#pragma unroll
        for (int j = 0; j < 2; j++)
            __builtin_amdgcn_global_load_lds(
                (const __attribute__((address_space(1))) unsigned int*)(Ap[j] + k0),
                (__attribute__((address_space(3))) unsigned int*)(As + (32 * w + 16 * j) * 32),
                16, 0, 0);

        const size_t boff = (size_t)(k0 + 2 * kh) * H_DIM;
        floatx4 b0 = *(const floatx4*)(Bp + boff);
        floatx4 b1 = *(const floatx4*)(Bp + boff + H_DIM);
#pragma unroll
        for (int j2 = 0; j2 < 4; j2++) {
            unsigned int p = (unsigned int)f2bf(b0[j2]) |
                             ((unsigned int)f2bf(b1[j2]) << 16);
            *(unsigned int*)&Bs[(n4 * 4 + j2) * 40 + 2 * kh] = p;
        }
        __syncthreads();

        short8 af[2], bfr[4];
#pragma unroll
        for (int mt = 0; mt < 2; mt++)
            af[mt] = *(const short8*)&As[(32 * w + mt * 16 + ml) * 32 + q * 8];
#pragma unroll
        for (int nt = 0; nt < 4; nt++)
            bfr[nt] = *(const short8*)&Bs[(nt * 16 + ml) * 40 + q * 8];
#pragma unroll
        for (int mt = 0; mt < 2; mt++)
#pragma unroll
            for (int nt = 0; nt < 4; nt++)
                acc[mt][nt] = __builtin_amdgcn_mfma_f32_16x16x32_bf16(
                    af[mt], bfr[nt], acc[mt][nt], 0, 0, 0);
        __syncthreads();
    }

#pragma unroll
    for (int mt = 0; mt < 2; mt++)
#pragma unroll
        for (int r = 0; r < 4; r++) {
            const int rloc = 32 * w + mt * 16 + q * 4 + r;
            const int rl = mtile * BM + rloc;
            if (rl < n) {
                const int t = toks[rloc];
#pragma unroll
                for (int nt = 0; nt < 4; nt++)
                    atomicAdd(&y[(size_t)t * H_DIM + ntile * 64 + nt * 16 + ml],
                              acc[mt][nt][r]);
            }
        }
}

// ---------------------------------------------------------------------------
extern "C" void kernel_launch(void* const* d_in, const int* in_sizes, int n_in,
                              void* d_out, int out_size, void* d_ws, size_t ws_size,
                              hipStream_t stream) {
    const float* x  = (const float*)d_in[0];
    const float* wr = (const float*)d_in[1];
    const float* wg = (const float*)d_in[2];
    const float* wu = (const float*)d_in[3];
    const float* wd = (const float*)d_in[4];
    float* y = (float*)d_out;

    char* ws = (char*)d_ws;
    int*    counts    = (int*)(ws + WS_OFF_COUNTS);
    int*    offsets   = (int*)(ws + WS_OFF_OFFSETS);
    int*    topk_idx  = (int*)(ws + WS_OFF_TOPKIDX);
    float*  topk_w    = (float*)(ws + WS_OFF_TOPKW);
    int*    row_token = (int*)(ws + WS_OFF_ROWTOK);
    float*  row_w     = (float*)(ws + WS_OFF_ROWW);
    int*    tile_e    = (int*)(ws + WS_OFF_TILEE);
    int*    tile_m    = (int*)(ws + WS_OFF_TILEM);
    int*    tile_c    = (int*)(ws + WS_OFF_TILEC);
    ushort* Xg        = (ushort*)(ws + WS_OFF_XG);
    ushort* h1        = (ushort*)(ws + WS_OFF_H1);

    hipMemsetAsync(counts, 0, 64, stream);
    hipMemsetAsync(y, 0, (size_t)T_TOK * H_DIM * sizeof(float), stream);

    router_kernel<<<T_TOK, 64, 0, stream>>>(x, wr, counts, topk_idx, topk_w);
    scatter_kernel<<<1, 256, 0, stream>>>(counts, offsets, topk_idx, topk_w,
                                          row_token, row_w, tile_e, tile_m, tile_c);
    gather_x_kernel<<<N_ASSIGN, 256, 0, stream>>>(x, row_token, Xg);
    gemm_gu_kernel<<<dim3(I_DIM / 64, TILE_MAX), 256, 0, stream>>>(
        Xg, wg, wu, offsets, row_w, tile_e, tile_m, tile_c, h1);
    gemm_down_kernel<<<dim3(H_DIM / 64, TILE_MAX, 2), 256, 0, stream>>>(
        h1, wd, offsets, row_token, tile_e, tile_m, tile_c, y);
}